// Round 7
// baseline (4394.017 us; speedup 1.0000x reference)
//
#include <hip/hip_runtime.h>
#include <hip/hip_bf16.h>

#define BATCH 64
#define SEQT  2048
#define FEAT  64
#define HID   128
#define G4    512              // 4*HID
#define CHUNK 16
#define NCHUNK (SEQT / CHUNK)  // 128
#define RPB   16               // batch-rows per block (= MFMA M)
#define NRG   (BATCH / RPB)    // 4 row-groups
#define HAP   136              // hA row stride (shorts): 16B-read bank-spread

using short8  = __attribute__((ext_vector_type(8))) short;   // 8 x bf16
using floatx4 = __attribute__((ext_vector_type(4))) float;   // MFMA C/D

// lgkm-only barrier: global prefetch loads / out stores stay in flight.
#define BAR_LGKM() asm volatile("s_waitcnt lgkmcnt(0)\n\ts_barrier" ::: "memory")

__device__ __forceinline__ float sigmoidf_(float x) {
    return __builtin_amdgcn_rcpf(1.0f + __expf(-x));
}
__device__ __forceinline__ float seluf_(float x) {
    const float a = 1.6732632423543772f;
    const float s = 1.0507009873554805f;
    return x > 0.0f ? s * x : s * a * (__expf(x) - 1.0f);
}
__device__ __forceinline__ unsigned short f2bf_(float f) {
    unsigned u = __float_as_uint(f);
    u += 0x7FFFu + ((u >> 16) & 1u);
    return (unsigned short)(u >> 16);
}

// ---------- prep: x fp32 -> bf16 (same [B][T][64] layout) ----------
__global__ __launch_bounds__(256) void prep_x(const float* __restrict__ x,
                                              unsigned short* __restrict__ xbf) {
    int idx = blockIdx.x * 256 + threadIdx.x;      // 1,048,576 threads x 8 elems
    const float4* src = (const float4*)x;
    float4 a = src[idx * 2], b = src[idx * 2 + 1];
    short8 v;
    v[0] = (short)f2bf_(a.x); v[1] = (short)f2bf_(a.y);
    v[2] = (short)f2bf_(a.z); v[3] = (short)f2bf_(a.w);
    v[4] = (short)f2bf_(b.x); v[5] = (short)f2bf_(b.y);
    v[6] = (short)f2bf_(b.z); v[7] = (short)f2bf_(b.w);
    *(short8*)&xbf[idx * 8] = v;
}

// ---------- fused two-layer LSTM, 16-row-batched MFMA ----------
// 8 blocks x 512 threads (8 waves, 2/SIMD, <=256 VGPR).
// Blocks [0,4):  layer 1, row-group rg (rows rg*16..+16).
// Blocks [4,8):  layer 2, row-group rg, lagging l1 by >=2 chunks (flag c+2
//                spin) so per-step h1 prefetch one step ahead is always safe.
// Wave w owns hidden cols [w*16,w*16+16); lane: c16 = A-row (batch row) and
// D-col (hidden col), quad = k-slice / D-row group. Per step per wave:
//   l1: 8 proj MFMA (x@W1, K=64, C preloaded with bias) + 16 rec MFMA
//   l2: 16 proj MFMA (h1@W2, K=128) + 16 rec MFMA
// z arrives fully summed in the accumulator (bias+proj+rec) -> zero z-adds.
// h exchanged via padded LDS ping-pong; h1 handoff via IC write-through
// relaxed-agent atomics (R0-proven protocol).
__global__ __launch_bounds__(512)
void fused_lstm(const unsigned short* __restrict__ xbf,   // [B][T][64] bf16
                const float* __restrict__ U1,             // [128][512]
                const float* __restrict__ b1,             // [512]
                const float* __restrict__ U2,
                const float* __restrict__ b2,
                const float* __restrict__ W1,             // [64][512]
                const float* __restrict__ W2,             // [128][512]
                unsigned long long* __restrict__ h1g,     // 32 MB ws, u64 view
                unsigned* __restrict__ flags,             // [NRG]
                float* __restrict__ out) {                // [B][T][128] fp32
    const int  bid = (int)blockIdx.x;
    const bool l2w = bid >= NRG;
    const int  rg  = l2w ? bid - NRG : bid;
    const int tid  = threadIdx.x;
    const int w    = tid >> 6;
    const int lane = tid & 63;
    const int c16  = lane & 15;
    const int quad = lane >> 4;
    const int hcol = w * 16 + c16;

    __shared__ __align__(16) short hA[2][RPB][HAP];        // 8.7 KB h ping-pong
    __shared__ __align__(16) short h1buf[CHUNK][RPB][HID]; // 64 KB (l1 only)

    // ---- recurrent weights U -> B-fragments (verified layout) ----
    const float* U = l2w ? U2 : U1;
    short8 bfrag[4][4];                 // [kc][gate]
#pragma unroll
    for (int g = 0; g < 4; ++g) {
        const float* Ucol = U + (size_t)(g * 128 + hcol);
#pragma unroll
        for (int kc = 0; kc < 4; ++kc) {
            short8 v;
#pragma unroll
            for (int jj = 0; jj < 8; ++jj)
                v[jj] = (short)f2bf_(Ucol[(size_t)(kc * 32 + quad * 8 + jj) * G4]);
            bfrag[kc][g] = v;
        }
    }
    // bias as MFMA C-init (all 4 D-rows share the lane's column)
    const float* bb = l2w ? b2 : b1;
    floatx4 biasC[4];
#pragma unroll
    for (int g = 0; g < 4; ++g) {
        float bv = bb[g * 128 + hcol];
        floatx4 t = {bv, bv, bv, bv};
        biasC[g] = t;
    }

    // zero h(-1)
    for (int i = tid; i < 2 * RPB * HAP; i += 512) ((short*)hA)[i] = 0;
    float cst[4] = {0.f, 0.f, 0.f, 0.f};     // 4 rows' cell state per lane
    __syncthreads();

    if (!l2w) {
        // ================= LAYER 1 =================
        short8 wfrag[2][4];              // W1 B-fragments, K=64
#pragma unroll
        for (int g = 0; g < 4; ++g) {
            const float* Wcol = W1 + (size_t)(g * 128 + hcol);
#pragma unroll
            for (int kc = 0; kc < 2; ++kc) {
                short8 v;
#pragma unroll
                for (int jj = 0; jj < 8; ++jj)
                    v[jj] = (short)f2bf_(Wcol[(size_t)(kc * 32 + quad * 8 + jj) * G4]);
                wfrag[kc][g] = v;
            }
        }
        const unsigned short* xrow = xbf + (size_t)(rg * RPB + c16) * SEQT * FEAT;
        unsigned long long*   h1o  = h1g + (size_t)rg * (SEQT * RPB * HID / 4);

        short8 axA[2], axB[2];
#pragma unroll
        for (int kc = 0; kc < 2; ++kc)   // prefetch t=0
            axA[kc] = *(const short8*)&xrow[kc * 32 + quad * 8];

#define L1_STEP(S, CUR, NXT) do {                                                 \
    short8 af_[4];                                                                \
    _Pragma("unroll")                                                             \
    for (int kc = 0; kc < 4; ++kc)                                                \
        af_[kc] = *(const short8*)&hA[(S) & 1][c16][kc * 32 + quad * 8];          \
    const int t_  = c * CHUNK + (S);                                              \
    const int tn_ = (t_ + 1 < SEQT) ? t_ + 1 : t_;                                \
    _Pragma("unroll")                                                             \
    for (int kc = 0; kc < 2; ++kc)                                                \
        NXT[kc] = *(const short8*)&xrow[(size_t)tn_ * FEAT + kc * 32 + quad * 8]; \
    floatx4 acc_[4];                                                              \
    _Pragma("unroll")                                                             \
    for (int g = 0; g < 4; ++g)                                                   \
        acc_[g] = __builtin_amdgcn_mfma_f32_16x16x32_bf16(CUR[0], wfrag[0][g], biasC[g], 0, 0, 0); \
    _Pragma("unroll")                                                             \
    for (int g = 0; g < 4; ++g)                                                   \
        acc_[g] = __builtin_amdgcn_mfma_f32_16x16x32_bf16(CUR[1], wfrag[1][g], acc_[g], 0, 0, 0);  \
    _Pragma("unroll")                                                             \
    for (int kc = 0; kc < 4; ++kc)                                                \
        _Pragma("unroll")                                                         \
        for (int g = 0; g < 4; ++g)                                               \
            acc_[g] = __builtin_amdgcn_mfma_f32_16x16x32_bf16(af_[kc], bfrag[kc][g], acc_[g], 0, 0, 0); \
    _Pragma("unroll")                                                             \
    for (int r = 0; r < 4; ++r) {                                                 \
        int row_ = quad * 4 + r;                                                  \
        float ig = sigmoidf_(acc_[0][r]);                                         \
        float fg = sigmoidf_(acc_[1][r]);                                         \
        float gg = seluf_(acc_[2][r]);                                            \
        float og = sigmoidf_(acc_[3][r]);                                         \
        cst[r] = fg * cst[r] + ig * gg;                                           \
        float h_ = og * seluf_(cst[r]);                                           \
        unsigned short h16 = f2bf_(h_);                                           \
        hA[((S) + 1) & 1][row_][hcol] = (short)h16;                               \
        h1buf[S][row_][hcol] = (short)h16;                                        \
    }                                                                             \
    BAR_LGKM();                                                                   \
} while (0)

        for (int c = 0; c < NCHUNK; ++c) {
            for (int sp = 0; sp < CHUNK; sp += 2) {
                L1_STEP(sp,     axA, axB);
                L1_STEP(sp + 1, axB, axA);
            }
            // flush h1 chunk: 8192 u64 write-through stores (coherent at IC)
            const unsigned long long* hb64 = (const unsigned long long*)&h1buf[0][0][0];
            unsigned long long* dst = h1o + (size_t)c * (CHUNK * RPB * HID / 4);
#pragma unroll
            for (int i = 0; i < 16; ++i)
                __hip_atomic_store(dst + tid + i * 512, hb64[tid + i * 512],
                                   __ATOMIC_RELAXED, __HIP_MEMORY_SCOPE_AGENT);
            __syncthreads();     // per-wave vmcnt(0) drain: stores reached IC
            if (tid == 0)
                __hip_atomic_store(&flags[rg], (unsigned)(c + 1),
                                   __ATOMIC_RELAXED, __HIP_MEMORY_SCOPE_AGENT);
        }
#undef L1_STEP
    } else {
        // ================= LAYER 2 =================
        short8 wfrag[4][4];              // W2 B-fragments, K=128
#pragma unroll
        for (int g = 0; g < 4; ++g) {
            const float* Wcol = W2 + (size_t)(g * 128 + hcol);
#pragma unroll
            for (int kc = 0; kc < 4; ++kc) {
                short8 v;
#pragma unroll
                for (int jj = 0; jj < 8; ++jj)
                    v[jj] = (short)f2bf_(Wcol[(size_t)(kc * 32 + quad * 8 + jj) * G4]);
                wfrag[kc][g] = v;
            }
        }
        unsigned long long* h1i = h1g + (size_t)rg * (SEQT * RPB * HID / 4);
        const int koff = quad * 2;       // u64 offset within a row's 128-short slice

#define H1_LOAD(T_, DST) do {                                                     \
    size_t b64_ = ((size_t)(T_) * RPB + c16) * (HID / 4);                         \
    _Pragma("unroll")                                                             \
    for (int kc = 0; kc < 4; ++kc) {                                              \
        union { unsigned long long q[2]; short8 v; } u_;                          \
        u_.q[0] = __hip_atomic_load(h1i + b64_ + kc * 8 + koff,                   \
                                    __ATOMIC_RELAXED, __HIP_MEMORY_SCOPE_AGENT);  \
        u_.q[1] = __hip_atomic_load(h1i + b64_ + kc * 8 + koff + 1,               \
                                    __ATOMIC_RELAXED, __HIP_MEMORY_SCOPE_AGENT);  \
        DST[kc] = u_.v;                                                           \
    }                                                                             \
} while (0)

#define L2_STEP(S, CUR, NXT) do {                                                 \
    short8 af_[4];                                                                \
    _Pragma("unroll")                                                             \
    for (int kc = 0; kc < 4; ++kc)                                                \
        af_[kc] = *(const short8*)&hA[(S) & 1][c16][kc * 32 + quad * 8];          \
    const int t_  = c * CHUNK + (S);                                              \
    const int tn_ = (t_ + 1 < SEQT) ? t_ + 1 : t_;                                \
    H1_LOAD(tn_, NXT);                                                            \
    floatx4 acc_[4];                                                              \
    _Pragma("unroll")                                                             \
    for (int g = 0; g < 4; ++g)                                                   \
        acc_[g] = __builtin_amdgcn_mfma_f32_16x16x32_bf16(CUR[0], wfrag[0][g], biasC[g], 0, 0, 0); \
    _Pragma("unroll")                                                             \
    for (int kc = 1; kc < 4; ++kc)                                                \
        _Pragma("unroll")                                                         \
        for (int g = 0; g < 4; ++g)                                               \
            acc_[g] = __builtin_amdgcn_mfma_f32_16x16x32_bf16(CUR[kc], wfrag[kc][g], acc_[g], 0, 0, 0); \
    _Pragma("unroll")                                                             \
    for (int kc = 0; kc < 4; ++kc)                                                \
        _Pragma("unroll")                                                         \
        for (int g = 0; g < 4; ++g)                                               \
            acc_[g] = __builtin_amdgcn_mfma_f32_16x16x32_bf16(af_[kc], bfrag[kc][g], acc_[g], 0, 0, 0); \
    _Pragma("unroll")                                                             \
    for (int r = 0; r < 4; ++r) {                                                 \
        int row_ = quad * 4 + r;                                                  \
        float ig = sigmoidf_(acc_[0][r]);                                         \
        float fg = sigmoidf_(acc_[1][r]);                                         \
        float gg = seluf_(acc_[2][r]);                                            \
        float og = sigmoidf_(acc_[3][r]);                                         \
        cst[r] = fg * cst[r] + ig * gg;                                           \
        float h_ = og * seluf_(cst[r]);                                           \
        hA[((S) + 1) & 1][row_][hcol] = (short)f2bf_(h_);                         \
        out[((size_t)(rg * RPB + row_) * SEQT + t_) * HID + hcol] = h_;           \
    }                                                                             \
    BAR_LGKM();                                                                   \
} while (0)

        short8 ahA[4], ahB[4];
        for (int c = 0; c < NCHUNK; ++c) {
            // spin for l1 lead >= 2 chunks -> step-15 prefetch of chunk c+1 is safe
            if (tid == 0) {
                unsigned tgt = (unsigned)((c + 2 < NCHUNK) ? c + 2 : NCHUNK);
                while (__hip_atomic_load(&flags[rg], __ATOMIC_RELAXED,
                                         __HIP_MEMORY_SCOPE_AGENT) < tgt)
                    __builtin_amdgcn_s_sleep(4);
            }
            __syncthreads();
            if (c == 0) H1_LOAD(0, ahA);
            for (int sp = 0; sp < CHUNK; sp += 2) {
                L2_STEP(sp,     ahA, ahB);
                L2_STEP(sp + 1, ahB, ahA);
            }
        }
#undef L2_STEP
#undef H1_LOAD
    }
}

// ---------- host launch ----------
// ws layout: [0,32MB) h1 bf16 pipe | [32MB,48MB) x bf16 | [48MB,+16B) flags
extern "C" void kernel_launch(void* const* d_in, const int* in_sizes, int n_in,
                              void* d_out, int out_size, void* d_ws, size_t ws_size,
                              hipStream_t stream) {
    const float* x  = (const float*)d_in[0];
    const float* W1 = (const float*)d_in[1];
    const float* U1 = (const float*)d_in[2];
    const float* b1 = (const float*)d_in[3];
    const float* W2 = (const float*)d_in[4];
    const float* U2 = (const float*)d_in[5];
    const float* b2 = (const float*)d_in[6];
    float* out = (float*)d_out;

    const size_t H1_BYTES = (size_t)BATCH * SEQT * HID * 2;   // 32 MB
    const size_t X_BYTES  = (size_t)BATCH * SEQT * FEAT * 2;  // 16 MB

    unsigned long long* h1g = (unsigned long long*)d_ws;
    unsigned short*     xbf = (unsigned short*)((char*)d_ws + H1_BYTES);
    unsigned*           flags = (unsigned*)((char*)d_ws + H1_BYTES + X_BYTES);

    hipMemsetAsync(flags, 0, NRG * sizeof(unsigned), stream);

    prep_x<<<dim3(4096), dim3(256), 0, stream>>>(x, xbf);

    fused_lstm<<<dim3(2 * NRG), dim3(512), 0, stream>>>(
        xbf, U1, b1, U2, b2, W1, W2, h1g, flags, out);
}

// Round 8
// 1286.580 us; speedup vs baseline: 3.4153x; 3.4153x over previous
//
#include <hip/hip_runtime.h>
#include <hip/hip_bf16.h>

#define BATCH 64
#define SEQT  2048
#define FEAT  64
#define HID   128
#define G4    512              // 4*HID
#define CHUNK 16
#define NCHUNK (SEQT / CHUNK)  // 128
#define XSP  68                // xs row stride (floats), padded vs 64
#define H1P  136               // h1c row stride (shorts), padded vs 128
#define XZP  516               // xzbuf row stride (floats), padded vs 512

using short8  = __attribute__((ext_vector_type(8))) short;   // 8 x bf16 (4 VGPRs)
using floatx4 = __attribute__((ext_vector_type(4))) float;   // MFMA C/D

// lgkm-only barrier for the per-step sync: does NOT drain vmcnt, so the
// chunk-level global prefetch loads / output stores stay in flight across
// the 16 step barriers. "memory" clobber pins all LDS ops. Full
// __syncthreads() is retained at chunk boundaries (its vmcnt(0) drain is the
// release ordering for the IC write-through handoff).
#define BAR_LGKM() asm volatile("s_waitcnt lgkmcnt(0)\n\ts_barrier" ::: "memory")

// ---------- math helpers ----------
__device__ __forceinline__ float sigmoidf_(float x) {
    return __builtin_amdgcn_rcpf(1.0f + __expf(-x));
}
__device__ __forceinline__ float seluf_(float x) {
    const float a = 1.6732632423543772f;
    const float s = 1.0507009873554805f;
    return x > 0.0f ? s * x : s * a * (__expf(x) - 1.0f);
}
// fp32 -> bf16 bits, round-to-nearest-even
__device__ __forceinline__ unsigned short f2bf_(float f) {
    unsigned u = __float_as_uint(f);
    u += 0x7FFFu + ((u >> 16) & 1u);
    return (unsigned short)(u >> 16);
}

// ---------- fused two-layer LSTM, wavefront-pipelined ----------
// (R0 structure, measured 1292 us: 128 blocks x 512 threads, 2 waves/SIMD.)
// Blocks [0,64):   layer 1, row b: per chunk builds xz1 = x@W1+b1 via MFMA,
//                  16 rec steps, publishes bf16 h1 chunk via write-through
//                  relaxed agent atomics (coherent at IC), then flag.
// Blocks [64,128): layer 2, row b: spins on flag, stages h1 chunk, builds
//                  xz2 = h1c@W2+b2 via MFMA, 16 rec steps, writes fp32 out.
// R8 deltas vs R0: lgkm-only step barriers; 2+2 split MFMA chains in the
// rec step; xq read issued before af reads.
__global__ __launch_bounds__(512)
__attribute__((amdgpu_waves_per_eu(2, 2)))
void fused_lstm(const float* __restrict__ x,                 // [B][T][64] fp32
                const float* __restrict__ W1,                // [64][512] fp32
                const float* __restrict__ U1,                // [128][512] fp32
                const float* __restrict__ b1,                // [512]
                const float* __restrict__ W2,                // [128][512] fp32
                const float* __restrict__ U2,
                const float* __restrict__ b2,
                unsigned long long* __restrict__ h1g,        // [B][T][128] bf16 (ws), u64 view
                unsigned* __restrict__ flags,                // [B] (zeroed by memset)
                float* __restrict__ out) {                   // [B][T][128] fp32
    const bool l2  = blockIdx.x >= BATCH;
    const int  b   = l2 ? ((int)blockIdx.x - BATCH) : (int)blockIdx.x;
    const int tid  = threadIdx.x;
    const int w    = tid >> 6;
    const int lane = tid & 63;
    const int c16  = lane & 15;
    const int quad = lane >> 4;
    const int j    = w * 16 + c16;            // output column this thread owns

    __shared__ __align__(16) short hA[2][HID];           // bf16 h ping-pong
    __shared__ __align__(16) float xzbuf[CHUNK * XZP];   // fp32 z-pre, gate-interleaved, padded
    __shared__ __align__(16) float xs[CHUNK * XSP];      // l1: x chunk staged (padded)
    __shared__ __align__(16) short h1c[CHUNK * H1P];     // l2: h1 chunk staged (padded)
    __shared__ __align__(16) short h1buf[CHUNK * HID];   // l1: h chunk bf16 (flush buffer)
    __shared__ __align__(16) float hbuf[CHUNK * HID];    // l2: h chunk fp32 (out buffer)

    // ---- stage recurrent-weight fragments U (l1->U1, l2->U2), K=128 ----
    const float* U = l2 ? U2 : U1;
    short8 bfrag[4][4];                 // [gate][kc]
#pragma unroll
    for (int g = 0; g < 4; ++g) {
        const float* Ucol = U + (size_t)(g * 128 + j);
#pragma unroll
        for (int kc = 0; kc < 4; ++kc) {
            short8 v;
#pragma unroll
            for (int jj = 0; jj < 8; ++jj) {
                int k = kc * 32 + quad * 8 + jj;
                v[jj] = (short)f2bf_(Ucol[(size_t)k * G4]);
            }
            bfrag[g][kc] = v;
        }
    }

    // ---- input-projection fragments: l1 -> W1 (K=64, kc<2), l2 -> W2 (K=128) ----
    const float* Wp = l2 ? W2 : W1;
    const int KCW = l2 ? 4 : 2;
    short8 wfrag[4][4];                 // [gate][kc]; l1 kc>=2 dead
#pragma unroll
    for (int g = 0; g < 4; ++g) {
        const float* Wcol = Wp + (size_t)(g * 128 + j);
#pragma unroll
        for (int kc = 0; kc < 4; ++kc) {
            if (kc < KCW) {
                short8 v;
#pragma unroll
                for (int jj = 0; jj < 8; ++jj) {
                    int k = kc * 32 + quad * 8 + jj;
                    v[jj] = (short)f2bf_(Wcol[(size_t)k * G4]);
                }
                wfrag[g][kc] = v;
            }
        }
    }
    const float* bb = l2 ? b2 : b1;
    const float4 bias4 = make_float4(bb[j], bb[128 + j], bb[256 + j], bb[384 + j]);

    const float* xb = x + (size_t)b * SEQT * FEAT;
    if (!l2) {   // prologue: stage x chunk 0 into padded LDS (256 float4)
        if (tid < 256) {
            float4 v = ((const float4*)xb)[tid];
            *(float4*)&xs[(tid >> 4) * XSP + ((tid & 15) << 2)] = v;
        }
    }
    if (tid < HID) hA[0][tid] = 0;            // h(-1) = 0
    float cst = 0.0f;                          // cell state (replicated x4 quads)
    floatx4 zero4 = {0.f, 0.f, 0.f, 0.f};
    __syncthreads();

    float*              out_b = out + (size_t)b * SEQT * HID;
    unsigned long long* h1g_b = h1g + (size_t)b * (SEQT * HID / 4);  // 65536 u64/row

    for (int c = 0; c < NCHUNK; ++c) {
        float4 pf;
        if (!l2) {
            // prefetch next x chunk (4 KB, contiguous; stays in flight across
            // the whole chunk -- step barriers are lgkm-only)
            if (c + 1 < NCHUNK && tid < 256)
                pf = ((const float4*)(xb + (size_t)(c + 1) * CHUNK * FEAT))[tid];
            // ---- build xz1 chunk: [16 t] x [512] = x_s @ W1 + b1, K=64 ----
            short8 ax[2];
#pragma unroll
            for (int kc = 0; kc < 2; ++kc) {
                const float* p = &xs[c16 * XSP + kc * 32 + quad * 8];
                float4 f0 = *(const float4*)p;
                float4 f1 = *(const float4*)(p + 4);
                short8 v;
                v[0] = (short)f2bf_(f0.x); v[1] = (short)f2bf_(f0.y);
                v[2] = (short)f2bf_(f0.z); v[3] = (short)f2bf_(f0.w);
                v[4] = (short)f2bf_(f1.x); v[5] = (short)f2bf_(f1.y);
                v[6] = (short)f2bf_(f1.z); v[7] = (short)f2bf_(f1.w);
                ax[kc] = v;
            }
            floatx4 acc1[4];
#pragma unroll
            for (int g = 0; g < 4; ++g) {
                floatx4 t = __builtin_amdgcn_mfma_f32_16x16x32_bf16(ax[0], wfrag[g][0], zero4, 0, 0, 0);
                acc1[g] = __builtin_amdgcn_mfma_f32_16x16x32_bf16(ax[1], wfrag[g][1], t, 0, 0, 0);
            }
            // D mapping: col=lane&15 (j), row=quad*4+reg (timestep)
#pragma unroll
            for (int r = 0; r < 4; ++r) {
                int srow = quad * 4 + r;
                *(float4*)&xzbuf[srow * XZP + j * 4] =
                    make_float4(acc1[0][r] + bias4.x, acc1[1][r] + bias4.y,
                                acc1[2][r] + bias4.z, acc1[3][r] + bias4.w);
            }
            __syncthreads();
        } else {
            // ---- wait for layer-1 chunk c, then stage + build xz2 chunk ----
            if (tid == 0) {
                while (__hip_atomic_load(&flags[b], __ATOMIC_RELAXED,
                                         __HIP_MEMORY_SCOPE_AGENT) < (unsigned)(c + 1))
                    __builtin_amdgcn_s_sleep(2);
            }
            __syncthreads();
            // stage h1 chunk: 512 x 8B cache-bypassing loads (coherent at IC)
            {
                unsigned long long hv = __hip_atomic_load(
                    h1g_b + (size_t)c * 512 + tid, __ATOMIC_RELAXED, __HIP_MEMORY_SCOPE_AGENT);
                int t = tid >> 5, kg = tid & 31;
                *(unsigned long long*)&h1c[t * H1P + kg * 4] = hv;
            }
            __syncthreads();

            // xz2[t][n] = sum_k h1c[t][k] * W2[k][n] + b2  (M=16, K=128)
            short8 ah[4];
#pragma unroll
            for (int kc = 0; kc < 4; ++kc)
                ah[kc] = *(const short8*)&h1c[c16 * H1P + kc * 32 + quad * 8];
            floatx4 acc2[4];
#pragma unroll
            for (int g = 0; g < 4; ++g) {
                floatx4 t = __builtin_amdgcn_mfma_f32_16x16x32_bf16(ah[0], wfrag[g][0], zero4, 0, 0, 0);
                t = __builtin_amdgcn_mfma_f32_16x16x32_bf16(ah[1], wfrag[g][1], t, 0, 0, 0);
                t = __builtin_amdgcn_mfma_f32_16x16x32_bf16(ah[2], wfrag[g][2], t, 0, 0, 0);
                acc2[g] = __builtin_amdgcn_mfma_f32_16x16x32_bf16(ah[3], wfrag[g][3], t, 0, 0, 0);
            }
#pragma unroll
            for (int r = 0; r < 4; ++r) {
                int srow = quad * 4 + r;
                *(float4*)&xzbuf[srow * XZP + j * 4] =
                    make_float4(acc2[0][r] + bias4.x, acc2[1][r] + bias4.y,
                                acc2[2][r] + bias4.z, acc2[3][r] + bias4.w);
            }
            __syncthreads();
        }

        // ---- 16 recurrent steps (lgkm-only barriers; 2+2 MFMA chains) ----
#pragma unroll 2
        for (int s = 0; s < CHUNK; ++s) {
            // xq first: its LDS latency hides under the MFMA chain
            float4 xq = *(const float4*)&xzbuf[s * XZP + j * 4];
            const short* hb = &hA[s & 1][0];
            short8 af[4];
#pragma unroll
            for (int kc = 0; kc < 4; ++kc)
                af[kc] = *(const short8*)&hb[kc * 32 + quad * 8];

            // two 2-deep chains per gate; combine on the used element only
            floatx4 accA[4], accB[4];
#pragma unroll
            for (int g = 0; g < 4; ++g) {
                floatx4 t0 = __builtin_amdgcn_mfma_f32_16x16x32_bf16(af[0], bfrag[g][0], zero4, 0, 0, 0);
                accA[g] = __builtin_amdgcn_mfma_f32_16x16x32_bf16(af[1], bfrag[g][1], t0, 0, 0, 0);
                floatx4 t1 = __builtin_amdgcn_mfma_f32_16x16x32_bf16(af[2], bfrag[g][2], zero4, 0, 0, 0);
                accB[g] = __builtin_amdgcn_mfma_f32_16x16x32_bf16(af[3], bfrag[g][3], t1, 0, 0, 0);
            }

            float zi = accA[0][0] + accB[0][0] + xq.x;
            float zf = accA[1][0] + accB[1][0] + xq.y;
            float zg = accA[2][0] + accB[2][0] + xq.z;
            float zo = accA[3][0] + accB[3][0] + xq.w;
            float ig = sigmoidf_(zi), fg = sigmoidf_(zf);
            float gg = seluf_(zg),   og = sigmoidf_(zo);
            cst = fg * cst + ig * gg;
            float h = og * seluf_(cst);

            if (lane < 16) {                   // quad 0 publishes (all quads identical)
                unsigned short h16 = f2bf_(h);
                hA[(s + 1) & 1][j] = (short)h16;
                if (l2) hbuf[s * HID + j] = h;
                else    h1buf[s * HID + j] = (short)h16;
            }
            BAR_LGKM();
        }

        // ---- chunk boundary ----
        if (!l2) {
            // flush h1 chunk: 512 x 8B write-through stores (coherent at IC)
            unsigned long long hv = *(const unsigned long long*)&h1buf[tid * 4];
            __hip_atomic_store(h1g_b + (size_t)c * 512 + tid, hv,
                               __ATOMIC_RELAXED, __HIP_MEMORY_SCOPE_AGENT);
            // install prefetched x chunk
            if (c + 1 < NCHUNK && tid < 256)
                *(float4*)&xs[(tid >> 4) * XSP + ((tid & 15) << 2)] = pf;
            __syncthreads();   // per-wave vmcnt(0) drain: h1 stores reached IC
            if (tid == 0)
                __hip_atomic_store(&flags[b], (unsigned)(c + 1),
                                   __ATOMIC_RELAXED, __HIP_MEMORY_SCOPE_AGENT);
        } else {
            float4 hv = *(const float4*)&hbuf[tid * 4];
            *(float4*)&out_b[(size_t)c * CHUNK * HID + tid * 4] = hv;
            // next chunk's spin+syncthreads protects hbuf reuse
        }
    }
}

// ---------- host launch ----------
// ws layout:
//   [0, 32 MB)        h1 bf16  (layer-1 -> layer-2 pipe, IC-coherent atomics)
//   [32 MB, +256 B)   per-row chunk flags (zeroed via memsetAsync each call)
extern "C" void kernel_launch(void* const* d_in, const int* in_sizes, int n_in,
                              void* d_out, int out_size, void* d_ws, size_t ws_size,
                              hipStream_t stream) {
    const float* x  = (const float*)d_in[0];
    const float* W1 = (const float*)d_in[1];
    const float* U1 = (const float*)d_in[2];
    const float* b1 = (const float*)d_in[3];
    const float* W2 = (const float*)d_in[4];
    const float* U2 = (const float*)d_in[5];
    const float* b2 = (const float*)d_in[6];
    float* out = (float*)d_out;

    const size_t BT       = (size_t)BATCH * SEQT;
    const size_t H1_BYTES = BT * HID * 2;    // 32 MB

    unsigned long long* h1g   = (unsigned long long*)d_ws;
    unsigned*           flags = (unsigned*)((char*)d_ws + H1_BYTES);

    hipMemsetAsync(flags, 0, BATCH * sizeof(unsigned), stream);

    fused_lstm<<<dim3(2 * BATCH), dim3(512), 0, stream>>>(
        x, W1, U1, b1, W2, U2, b2, h1g, flags, out);
}

// Round 9
// 1258.653 us; speedup vs baseline: 3.4910x; 1.0222x over previous
//
#include <hip/hip_runtime.h>
#include <hip/hip_bf16.h>

#define BATCH 64
#define SEQT  2048
#define FEAT  64
#define HID   128
#define G4    512              // 4*HID
#define CHUNK 32
#define NCHUNK (SEQT / CHUNK)  // 64
#define XSP  68                // xs row stride (floats), padded vs 64
#define H1P  136               // h1c row stride (shorts), padded vs 128
#define XZP  516               // xzbuf row stride (floats), padded vs 512

using short8  = __attribute__((ext_vector_type(8))) short;   // 8 x bf16 (4 VGPRs)
using floatx4 = __attribute__((ext_vector_type(4))) float;   // MFMA C/D

// lgkm-only barrier for the per-step sync: does NOT drain vmcnt, so chunk-level
// global prefetch loads / fire-and-forget out stores stay in flight across the
// step barriers. Full __syncthreads() retained at chunk boundaries (its
// vmcnt(0) drain is the release ordering for the IC write-through handoff).
#define BAR_LGKM() asm volatile("s_waitcnt lgkmcnt(0)\n\ts_barrier" ::: "memory")

// ---------- math helpers ----------
__device__ __forceinline__ float sigmoidf_(float x) {
    return __builtin_amdgcn_rcpf(1.0f + __expf(-x));
}
__device__ __forceinline__ float seluf_(float x) {
    const float a = 1.6732632423543772f;
    const float s = 1.0507009873554805f;
    return x > 0.0f ? s * x : s * a * (__expf(x) - 1.0f);
}
// fp32 -> bf16 bits, round-to-nearest-even
__device__ __forceinline__ unsigned short f2bf_(float f) {
    unsigned u = __float_as_uint(f);
    u += 0x7FFFu + ((u >> 16) & 1u);
    return (unsigned short)(u >> 16);
}

// ---------- fused two-layer LSTM, wavefront-pipelined ----------
// (R0/R8 structure, measured 1287 us: 128 blocks x 512 threads, 2 waves/SIMD.)
// R9 deltas: CHUNK 16->32 (halves amortized chunk-boundary overhead: flag
// spin, IC stage, projection phase, flush, 2 full-drain barriers), and l2
// writes out fire-and-forget per step (drops hbuf + boundary flush; stores
// never drained by the lgkm-only step barriers).
__global__ __launch_bounds__(512)
__attribute__((amdgpu_waves_per_eu(2, 2)))
void fused_lstm(const float* __restrict__ x,                 // [B][T][64] fp32
                const float* __restrict__ W1,                // [64][512] fp32
                const float* __restrict__ U1,                // [128][512] fp32
                const float* __restrict__ b1,                // [512]
                const float* __restrict__ W2,                // [128][512] fp32
                const float* __restrict__ U2,
                const float* __restrict__ b2,
                unsigned long long* __restrict__ h1g,        // [B][T][128] bf16 (ws), u64 view
                unsigned* __restrict__ flags,                // [B] (zeroed by memset)
                float* __restrict__ out) {                   // [B][T][128] fp32
    const bool l2  = blockIdx.x >= BATCH;
    const int  b   = l2 ? ((int)blockIdx.x - BATCH) : (int)blockIdx.x;
    const int tid  = threadIdx.x;
    const int w    = tid >> 6;
    const int lane = tid & 63;
    const int c16  = lane & 15;
    const int quad = lane >> 4;
    const int j    = w * 16 + c16;            // output column this thread owns

    __shared__ __align__(16) short hA[2][HID];           // bf16 h ping-pong
    __shared__ __align__(16) float xzbuf[CHUNK * XZP];   // 66 KB fp32 z-pre, padded
    __shared__ __align__(16) float xs[CHUNK * XSP];      // 8.7 KB l1: x chunk (padded)
    __shared__ __align__(16) short h1c[CHUNK * H1P];     // 8.7 KB l2: h1 chunk (padded)
    __shared__ __align__(16) short h1buf[CHUNK * HID];   // 8 KB l1: h chunk flush buffer

    // ---- stage recurrent-weight fragments U (l1->U1, l2->U2), K=128 ----
    const float* U = l2 ? U2 : U1;
    short8 bfrag[4][4];                 // [gate][kc]
#pragma unroll
    for (int g = 0; g < 4; ++g) {
        const float* Ucol = U + (size_t)(g * 128 + j);
#pragma unroll
        for (int kc = 0; kc < 4; ++kc) {
            short8 v;
#pragma unroll
            for (int jj = 0; jj < 8; ++jj) {
                int k = kc * 32 + quad * 8 + jj;
                v[jj] = (short)f2bf_(Ucol[(size_t)k * G4]);
            }
            bfrag[g][kc] = v;
        }
    }

    // ---- input-projection fragments: l1 -> W1 (K=64, kc<2), l2 -> W2 (K=128) ----
    const float* Wp = l2 ? W2 : W1;
    const int KCW = l2 ? 4 : 2;
    short8 wfrag[4][4];                 // [gate][kc]; l1 kc>=2 dead
#pragma unroll
    for (int g = 0; g < 4; ++g) {
        const float* Wcol = Wp + (size_t)(g * 128 + j);
#pragma unroll
        for (int kc = 0; kc < 4; ++kc) {
            if (kc < KCW) {
                short8 v;
#pragma unroll
                for (int jj = 0; jj < 8; ++jj) {
                    int k = kc * 32 + quad * 8 + jj;
                    v[jj] = (short)f2bf_(Wcol[(size_t)k * G4]);
                }
                wfrag[g][kc] = v;
            }
        }
    }
    const float* bb = l2 ? b2 : b1;
    const float4 bias4 = make_float4(bb[j], bb[128 + j], bb[256 + j], bb[384 + j]);

    const float* xb = x + (size_t)b * SEQT * FEAT;
    if (!l2) {   // prologue: stage x chunk 0 into padded LDS (512 float4)
        float4 v = ((const float4*)xb)[tid];
        *(float4*)&xs[(tid >> 4) * XSP + ((tid & 15) << 2)] = v;
    }
    if (tid < HID) hA[0][tid] = 0;            // h(-1) = 0
    float cst = 0.0f;                          // cell state (replicated x4 quads)
    floatx4 zero4 = {0.f, 0.f, 0.f, 0.f};
    __syncthreads();

    float*              out_b = out + (size_t)b * SEQT * HID;
    unsigned long long* h1g_b = h1g + (size_t)b * (SEQT * HID / 4);  // 65536 u64/row

    for (int c = 0; c < NCHUNK; ++c) {
        float4 pf;
        if (!l2) {
            // prefetch next x chunk (8 KB, contiguous; stays in flight across
            // the whole chunk -- step barriers are lgkm-only)
            if (c + 1 < NCHUNK)
                pf = ((const float4*)(xb + (size_t)(c + 1) * CHUNK * FEAT))[tid];
            // ---- build xz1 chunk: [32 t] x [512] = x_s @ W1 + b1, K=64 ----
#pragma unroll
            for (int mt = 0; mt < 2; ++mt) {
                short8 ax[2];
#pragma unroll
                for (int kc = 0; kc < 2; ++kc) {
                    const float* p = &xs[(mt * 16 + c16) * XSP + kc * 32 + quad * 8];
                    float4 f0 = *(const float4*)p;
                    float4 f1 = *(const float4*)(p + 4);
                    short8 v;
                    v[0] = (short)f2bf_(f0.x); v[1] = (short)f2bf_(f0.y);
                    v[2] = (short)f2bf_(f0.z); v[3] = (short)f2bf_(f0.w);
                    v[4] = (short)f2bf_(f1.x); v[5] = (short)f2bf_(f1.y);
                    v[6] = (short)f2bf_(f1.z); v[7] = (short)f2bf_(f1.w);
                    ax[kc] = v;
                }
                floatx4 acc1[4];
#pragma unroll
                for (int g = 0; g < 4; ++g) {
                    floatx4 t = __builtin_amdgcn_mfma_f32_16x16x32_bf16(ax[0], wfrag[g][0], zero4, 0, 0, 0);
                    acc1[g] = __builtin_amdgcn_mfma_f32_16x16x32_bf16(ax[1], wfrag[g][1], t, 0, 0, 0);
                }
                // D mapping: col=lane&15 (j), row=quad*4+reg (timestep in tile)
#pragma unroll
                for (int r = 0; r < 4; ++r) {
                    int srow = mt * 16 + quad * 4 + r;
                    *(float4*)&xzbuf[srow * XZP + j * 4] =
                        make_float4(acc1[0][r] + bias4.x, acc1[1][r] + bias4.y,
                                    acc1[2][r] + bias4.z, acc1[3][r] + bias4.w);
                }
            }
            __syncthreads();
        } else {
            // ---- wait for layer-1 chunk c, then stage + build xz2 chunk ----
            if (tid == 0) {
                while (__hip_atomic_load(&flags[b], __ATOMIC_RELAXED,
                                         __HIP_MEMORY_SCOPE_AGENT) < (unsigned)(c + 1))
                    __builtin_amdgcn_s_sleep(2);
            }
            __syncthreads();
            // stage h1 chunk: 1024 x 8B cache-bypassing loads (coherent at IC)
#pragma unroll
            for (int i = 0; i < 2; ++i) {
                int idx = tid + i * 512;
                unsigned long long hv = __hip_atomic_load(
                    h1g_b + (size_t)c * 1024 + idx, __ATOMIC_RELAXED, __HIP_MEMORY_SCOPE_AGENT);
                *(unsigned long long*)&h1c[(idx >> 5) * H1P + (idx & 31) * 4] = hv;
            }
            __syncthreads();

            // xz2[t][n] = sum_k h1c[t][k] * W2[k][n] + b2  (two M=16 tiles, K=128)
#pragma unroll
            for (int mt = 0; mt < 2; ++mt) {
                short8 ah[4];
#pragma unroll
                for (int kc = 0; kc < 4; ++kc)
                    ah[kc] = *(const short8*)&h1c[(mt * 16 + c16) * H1P + kc * 32 + quad * 8];
                floatx4 acc2[4];
#pragma unroll
                for (int g = 0; g < 4; ++g) {
                    floatx4 t = __builtin_amdgcn_mfma_f32_16x16x32_bf16(ah[0], wfrag[g][0], zero4, 0, 0, 0);
                    t = __builtin_amdgcn_mfma_f32_16x16x32_bf16(ah[1], wfrag[g][1], t, 0, 0, 0);
                    t = __builtin_amdgcn_mfma_f32_16x16x32_bf16(ah[2], wfrag[g][2], t, 0, 0, 0);
                    acc2[g] = __builtin_amdgcn_mfma_f32_16x16x32_bf16(ah[3], wfrag[g][3], t, 0, 0, 0);
                }
#pragma unroll
                for (int r = 0; r < 4; ++r) {
                    int srow = mt * 16 + quad * 4 + r;
                    *(float4*)&xzbuf[srow * XZP + j * 4] =
                        make_float4(acc2[0][r] + bias4.x, acc2[1][r] + bias4.y,
                                    acc2[2][r] + bias4.z, acc2[3][r] + bias4.w);
                }
            }
            __syncthreads();
        }

        // ---- 32 recurrent steps (lgkm-only barriers; 2+2 MFMA chains) ----
#pragma unroll 2
        for (int s = 0; s < CHUNK; ++s) {
            // xq first: its LDS latency hides under the MFMA chain
            float4 xq = *(const float4*)&xzbuf[s * XZP + j * 4];
            const short* hb = &hA[s & 1][0];
            short8 af[4];
#pragma unroll
            for (int kc = 0; kc < 4; ++kc)
                af[kc] = *(const short8*)&hb[kc * 32 + quad * 8];

            // two 2-deep chains per gate; combine on the used element only
            floatx4 accA[4], accB[4];
#pragma unroll
            for (int g = 0; g < 4; ++g) {
                floatx4 t0 = __builtin_amdgcn_mfma_f32_16x16x32_bf16(af[0], bfrag[g][0], zero4, 0, 0, 0);
                accA[g] = __builtin_amdgcn_mfma_f32_16x16x32_bf16(af[1], bfrag[g][1], t0, 0, 0, 0);
                floatx4 t1 = __builtin_amdgcn_mfma_f32_16x16x32_bf16(af[2], bfrag[g][2], zero4, 0, 0, 0);
                accB[g] = __builtin_amdgcn_mfma_f32_16x16x32_bf16(af[3], bfrag[g][3], t1, 0, 0, 0);
            }

            float zi = accA[0][0] + accB[0][0] + xq.x;
            float zf = accA[1][0] + accB[1][0] + xq.y;
            float zg = accA[2][0] + accB[2][0] + xq.z;
            float zo = accA[3][0] + accB[3][0] + xq.w;
            float ig = sigmoidf_(zi), fg = sigmoidf_(zf);
            float gg = seluf_(zg),   og = sigmoidf_(zo);
            cst = fg * cst + ig * gg;
            float h = og * seluf_(cst);

            if (lane < 16) {                   // quad 0 publishes (all quads identical)
                unsigned short h16 = f2bf_(h);
                hA[(s + 1) & 1][j] = (short)h16;
                if (l2) out_b[(size_t)(c * CHUNK + s) * HID + j] = h;  // fire-and-forget
                else    h1buf[s * HID + j] = (short)h16;
            }
            BAR_LGKM();
        }

        // ---- chunk boundary ----
        if (!l2) {
            // flush h1 chunk: 1024 x 8B write-through stores (coherent at IC)
#pragma unroll
            for (int i = 0; i < 2; ++i) {
                int idx = tid + i * 512;
                unsigned long long hv = *(const unsigned long long*)&h1buf[idx * 4];
                __hip_atomic_store(h1g_b + (size_t)c * 1024 + idx, hv,
                                   __ATOMIC_RELAXED, __HIP_MEMORY_SCOPE_AGENT);
            }
            // install prefetched x chunk
            if (c + 1 < NCHUNK)
                *(float4*)&xs[(tid >> 4) * XSP + ((tid & 15) << 2)] = pf;
            __syncthreads();   // per-wave vmcnt(0) drain: h1 stores reached IC
            if (tid == 0)
                __hip_atomic_store(&flags[b], (unsigned)(c + 1),
                                   __ATOMIC_RELAXED, __HIP_MEMORY_SCOPE_AGENT);
        }
        // l2: out stores are fire-and-forget; next chunk's spin+syncthreads
        // protects xzbuf reuse.
    }
}

// ---------- host launch ----------
// ws layout:
//   [0, 32 MB)        h1 bf16  (layer-1 -> layer-2 pipe, IC-coherent atomics)
//   [32 MB, +256 B)   per-row chunk flags (zeroed via memsetAsync each call)
extern "C" void kernel_launch(void* const* d_in, const int* in_sizes, int n_in,
                              void* d_out, int out_size, void* d_ws, size_t ws_size,
                              hipStream_t stream) {
    const float* x  = (const float*)d_in[0];
    const float* W1 = (const float*)d_in[1];
    const float* U1 = (const float*)d_in[2];
    const float* b1 = (const float*)d_in[3];
    const float* W2 = (const float*)d_in[4];
    const float* U2 = (const float*)d_in[5];
    const float* b2 = (const float*)d_in[6];
    float* out = (float*)d_out;

    const size_t BT       = (size_t)BATCH * SEQT;
    const size_t H1_BYTES = BT * HID * 2;    // 32 MB

    unsigned long long* h1g   = (unsigned long long*)d_ws;
    unsigned*           flags = (unsigned*)((char*)d_ws + H1_BYTES);

    hipMemsetAsync(flags, 0, BATCH * sizeof(unsigned), stream);

    fused_lstm<<<dim3(2 * BATCH), dim3(512), 0, stream>>>(
        x, W1, U1, b1, W2, U2, b2, h1g, flags, out);
}